// Round 4
// baseline (248.618 us; speedup 1.0000x reference)
//
#include <hip/hip_runtime.h>
#include <math.h>

// B=4, T=48, W=8, H=8, C=32; d_ff=64; periods {2,3,4}. T%P==0 always.
// (1x1 + 3^4)/2 inception folded into one 81-tap conv (center tap 40).
// All tensors padded in L,P,W,H so the 81-tap loop is branch-free.
// R4: tap-split — 3 waves/block each take one dl slice (27 taps), LDS fp32
// atomic reduce, block epilogue. 3456 waves vs 1152.

typedef __attribute__((ext_vector_type(8))) short bf16x8;
typedef __attribute__((ext_vector_type(4))) float f32x4;
typedef unsigned short u16;

// ---- workspace element offsets (u16 units unless noted) ----
#define XB0 0
#define XB1 1331200            // 4 * 26*4*3200
#define XB2 2483200            // XB1 + 4 * 18*5*3200
#define XTOT 3558400           // XB2 + 4 * 14*6*3200
#define W1OFF XTOT             // 165888 bf16  [tap][o=64][c=32]
#define W2OFF (XTOT + 165888)  // 165888 bf16  [tap][o=32][c=64]
#define H1OFF (XTOT + 331776)  // h1pad3 (C=64)
#define HB0 0
#define HB1 2662400            // 4 * 26*4*6400
#define HB2 4966400            // HB1 + 4 * 18*5*6400
#define H1TOT 7116800
#define H2OFF_U16 (H1OFF + H1TOT)
#define H2_PER 393216          // fp32 per period: 192*64*32
#define PREP_N (XTOT + 331776)

__device__ __forceinline__ u16 f2bf(float f) {
    unsigned u = __float_as_uint(f);
    unsigned r = u + 0x7fffu + ((u >> 16) & 1u);
    return (u16)(r >> 16);
}
__device__ __forceinline__ float gelu_exact(float v) {
    return 0.5f * v * (1.0f + erff(v * 0.7071067811865476f));
}

// ---- prep: padded bf16 x (3 period layouts) + effective bf16 weights ----
__global__ __launch_bounds__(256) void prep(
    const float* __restrict__ x,
    const float* __restrict__ w1_0, const float* __restrict__ w1_1,
    const float* __restrict__ w2_0, const float* __restrict__ w2_1,
    u16* __restrict__ ws) {
    int i = blockIdx.x * 256 + threadIdx.x;
    if (i < XTOT) {
        int j, P, L;
        if (i < XB1)      { j = i;       P = 2; L = 24; }
        else if (i < XB2) { j = i - XB1; P = 3; L = 16; }
        else              { j = i - XB2; P = 4; L = 12; }
        int SZ = (L + 2) * (P + 2) * 3200;
        int b = j / SZ; int r = j - b * SZ;
        int c = r & 31; int s = r >> 5;
        int hp = s % 10; s /= 10;
        int wp = s % 10; s /= 10;
        int qp = s % (P + 2); int lp = s / (P + 2);
        float v = 0.f;
        if (lp >= 1 && lp <= L && qp >= 1 && qp <= P &&
            wp >= 1 && wp <= 8 && hp >= 1 && hp <= 8) {
            int t = (lp - 1) * P + (qp - 1);
            v = x[((b * 48 + t) * 64 + (wp - 1) * 8 + (hp - 1)) * 32 + c];
        }
        ws[i] = f2bf(v);
    } else if (i < W2OFF) {
        int j = i - W1OFF;
        int c = j & 31; int k = j >> 5;
        int o = k & 63; int tap = k >> 6;
        float v = 0.5f * w1_1[(o * 32 + c) * 81 + tap];
        if (tap == 40) v += 0.5f * w1_0[o * 32 + c];
        ws[i] = f2bf(v);
    } else if (i < PREP_N) {
        int j = i - W2OFF;
        int c = j & 63; int k = j >> 6;
        int o = k & 31; int tap = k >> 5;
        float v = 0.5f * w2_1[(o * 64 + c) * 81 + tap];
        if (tap == 40) v += 0.5f * w2_0[o * 64 + c];
        ws[i] = f2bf(v);
    }
}

// ---- conv1 (C32->C64) + GELU. Block = 192 thr (3 waves); wave = dl slice.
template<int P>
__device__ __forceinline__ void conv1_body(
    const u16* __restrict__ xpad, const u16* __restrict__ w1b,
    u16* __restrict__ h1pad, int half, int bt) {
    constexpr int L = 48 / P;
    constexpr int XB = (P == 2) ? XB0 : (P == 3) ? XB1 : XB2;
    constexpr int HB = (P == 2) ? HB0 : (P == 3) ? HB1 : HB2;
    constexpr int XSTR = (L + 2) * (P + 2) * 3200;
    constexpr int HSTR = (L + 2) * (P + 2) * 6400;

    __shared__ float red[2048];   // [pos(64)][ch(32)]

    int tid = threadIdx.x;
    int lane = tid & 63;
    int dl = tid >> 6;            // wave id = dl slice
    int m = lane & 15, quad = lane >> 4;
    int b = bt / 48, t = bt - b * 48;
    int l = t / P, q = t - l * P;

    for (int i = tid; i < 2048; i += 192) red[i] = 0.f;
    __syncthreads();

    const u16* xb = xpad + XB + b * XSTR + (l * (P + 2) + q) * 3200
                    + dl * (P + 2) * 3200;
    const u16* wb = w1b + (half * 32 + m) * 32 + quad * 8 + dl * 3 * 9 * 2048;

    int sp[4];
#pragma unroll
    for (int mt = 0; mt < 4; ++mt) {
        int pos = mt * 16 + m;
        sp[mt] = ((pos >> 3) * 10 + (pos & 7)) * 32 + quad * 8;
    }

    f32x4 acc[4][2];
#pragma unroll
    for (int mt = 0; mt < 4; ++mt)
#pragma unroll
        for (int nt = 0; nt < 2; ++nt) acc[mt][nt] = f32x4{0.f, 0.f, 0.f, 0.f};

#pragma unroll
    for (int dq = 0; dq < 3; ++dq) {
        const u16* xt = xb + dq * 3200;
#pragma unroll
        for (int dwh = 0; dwh < 9; ++dwh) {
            int sd = ((dwh / 3) * 10 + (dwh % 3)) * 32;
            const u16* wp = wb + (dq * 9 + dwh) * 2048;
            bf16x8 bf[2];
#pragma unroll
            for (int nt = 0; nt < 2; ++nt)
                bf[nt] = *(const bf16x8*)(wp + nt * 512);
#pragma unroll
            for (int mt = 0; mt < 4; ++mt) {
                bf16x8 af = *(const bf16x8*)(xt + sp[mt] + sd);
#pragma unroll
                for (int nt = 0; nt < 2; ++nt)
                    acc[mt][nt] = __builtin_amdgcn_mfma_f32_16x16x32_bf16(
                        af, bf[nt], acc[mt][nt], 0, 0, 0);
            }
        }
    }

    // LDS fp32 atomic reduce (ds_add_f32): C layout row=quad*4+r, col=m
#pragma unroll
    for (int mt = 0; mt < 4; ++mt)
#pragma unroll
        for (int nt = 0; nt < 2; ++nt)
#pragma unroll
            for (int r = 0; r < 4; ++r) {
                int pos = mt * 16 + quad * 4 + r;
                atomicAdd(&red[pos * 32 + nt * 16 + m], acc[mt][nt][r]);
            }
    __syncthreads();

    u16* hb = h1pad + HB + b * HSTR + ((l + 1) * (P + 2) + (q + 1)) * 6400;
    for (int i = tid; i < 2048; i += 192) {
        int pos = i >> 5, ch = i & 31;
        int w = pos >> 3, h = pos & 7;
        hb[((w + 1) * 10 + (h + 1)) * 64 + half * 32 + ch] =
            f2bf(gelu_exact(red[i]));
    }
}

__global__ __launch_bounds__(192) void conv1_k(
    const u16* __restrict__ ws_x, const u16* __restrict__ ws_w1,
    u16* __restrict__ ws_h1) {
    int g = blockIdx.x;
    int per = g / 384; int rem = g - per * 384;
    int half = rem / 192; int bt = rem - half * 192;
    if (per == 0)      conv1_body<2>(ws_x, ws_w1, ws_h1, half, bt);
    else if (per == 1) conv1_body<3>(ws_x, ws_w1, ws_h1, half, bt);
    else               conv1_body<4>(ws_x, ws_w1, ws_h1, half, bt);
}

// ---- conv2 (C64->C32). Block = 192 thr (3 waves); wave = dl slice.
// Wave covers 32 positions (mh half) x 32 out-ch, K=64 per tap.
template<int P>
__device__ __forceinline__ void conv2_body(
    const u16* __restrict__ h1pad, const u16* __restrict__ w2b,
    float* __restrict__ orow, int mh, int bt) {
    constexpr int L = 48 / P;
    constexpr int HB = (P == 2) ? HB0 : (P == 3) ? HB1 : HB2;
    constexpr int HSTR = (L + 2) * (P + 2) * 6400;

    __shared__ float red[1024];   // [pos(32)][ch(32)]

    int tid = threadIdx.x;
    int lane = tid & 63;
    int dl = tid >> 6;
    int m = lane & 15, quad = lane >> 4;
    int b = bt / 48, t = bt - b * 48;
    int l = t / P, q = t - l * P;

    for (int i = tid; i < 1024; i += 192) red[i] = 0.f;
    __syncthreads();

    const u16* hbb = h1pad + HB + b * HSTR + (l * (P + 2) + q) * 6400
                     + dl * (P + 2) * 6400;
    const u16* wb = w2b + m * 64 + quad * 8 + dl * 3 * 9 * 2048;

    int sp[2];
#pragma unroll
    for (int mt = 0; mt < 2; ++mt) {
        int pos = mh * 32 + mt * 16 + m;
        sp[mt] = ((pos >> 3) * 10 + (pos & 7)) * 64 + quad * 8;
    }

    f32x4 acc[2][2];
#pragma unroll
    for (int mt = 0; mt < 2; ++mt)
#pragma unroll
        for (int nt = 0; nt < 2; ++nt) acc[mt][nt] = f32x4{0.f, 0.f, 0.f, 0.f};

#pragma unroll
    for (int dq = 0; dq < 3; ++dq) {
        const u16* ht = hbb + dq * 6400;
#pragma unroll
        for (int dwh = 0; dwh < 9; ++dwh) {
            int sd = ((dwh / 3) * 10 + (dwh % 3)) * 64;
            const u16* wp = wb + (dq * 9 + dwh) * 2048;
            bf16x8 bf[2][2];   // [nt][ks]
#pragma unroll
            for (int nt = 0; nt < 2; ++nt)
#pragma unroll
                for (int ks = 0; ks < 2; ++ks)
                    bf[nt][ks] = *(const bf16x8*)(wp + nt * 1024 + ks * 32);
#pragma unroll
            for (int mt = 0; mt < 2; ++mt)
#pragma unroll
                for (int ks = 0; ks < 2; ++ks) {
                    bf16x8 af = *(const bf16x8*)(ht + sp[mt] + sd + ks * 32);
#pragma unroll
                    for (int nt = 0; nt < 2; ++nt)
                        acc[mt][nt] = __builtin_amdgcn_mfma_f32_16x16x32_bf16(
                            af, bf[nt][ks], acc[mt][nt], 0, 0, 0);
                }
        }
    }

#pragma unroll
    for (int mt = 0; mt < 2; ++mt)
#pragma unroll
        for (int nt = 0; nt < 2; ++nt)
#pragma unroll
            for (int r = 0; r < 4; ++r) {
                int pos = mt * 16 + quad * 4 + r;   // local 0..31
                atomicAdd(&red[pos * 32 + nt * 16 + m], acc[mt][nt][r]);
            }
    __syncthreads();

    for (int i = tid; i < 1024; i += 192) {
        int pos = mh * 32 + (i >> 5), ch = i & 31;
        orow[pos * 32 + ch] = red[i];
    }
}

__global__ __launch_bounds__(192) void conv2_k(
    const u16* __restrict__ ws_h1, const u16* __restrict__ ws_w2,
    float* __restrict__ h2) {
    int g = blockIdx.x;
    int per = g / 384; int rem = g - per * 384;
    int mh = rem / 192; int bt = rem - mh * 192;
    float* orow = h2 + per * H2_PER + bt * 2048;
    if (per == 0)      conv2_body<2>(ws_h1, ws_w2, orow, mh, bt);
    else if (per == 1) conv2_body<3>(ws_h1, ws_w2, orow, mh, bt);
    else               conv2_body<4>(ws_h1, ws_w2, orow, mh, bt);
}

// ---- out = x + (h2_p0 + h2_p1 + h2_p2) / 3 ----
__global__ __launch_bounds__(256) void final_add(
    const float* __restrict__ x, const float* __restrict__ h2,
    float* __restrict__ out) {
    int i = blockIdx.x * 256 + threadIdx.x;
    float4 xv = ((const float4*)x)[i];
    float4 a = ((const float4*)h2)[i];
    float4 bv = ((const float4*)(h2 + H2_PER))[i];
    float4 cv = ((const float4*)(h2 + 2 * H2_PER))[i];
    const float s = 1.0f / 3.0f;
    float4 o;
    o.x = xv.x + (a.x + bv.x + cv.x) * s;
    o.y = xv.y + (a.y + bv.y + cv.y) * s;
    o.z = xv.z + (a.z + bv.z + cv.z) * s;
    o.w = xv.w + (a.w + bv.w + cv.w) * s;
    ((float4*)out)[i] = o;
}

extern "C" void kernel_launch(void* const* d_in, const int* in_sizes, int n_in,
                              void* d_out, int out_size, void* d_ws, size_t ws_size,
                              hipStream_t stream) {
    const float* x    = (const float*)d_in[0];
    const float* w1_0 = (const float*)d_in[1];
    const float* w1_1 = (const float*)d_in[2];
    const float* w2_0 = (const float*)d_in[3];
    const float* w2_1 = (const float*)d_in[4];
    float* out = (float*)d_out;

    u16* ws = (u16*)d_ws;
    u16* ws_x  = ws;
    u16* ws_w1 = ws + W1OFF;
    u16* ws_w2 = ws + W2OFF;
    u16* ws_h1 = ws + H1OFF;
    float* h2  = (float*)(ws + H2OFF_U16);

    hipMemsetAsync(ws_h1, 0, (size_t)H1TOT * 2, stream);
    prep<<<PREP_N / 256, 256, 0, stream>>>(x, w1_0, w1_1, w2_0, w2_1, ws);
    conv1_k<<<1152, 192, 0, stream>>>(ws_x, ws_w1, ws_h1);
    conv2_k<<<1152, 192, 0, stream>>>(ws_h1, ws_w2, h2);
    final_add<<<H2_PER / 4 / 256, 256, 0, stream>>>(x, h2, out);
}

// Round 5
// 241.671 us; speedup vs baseline: 1.0287x; 1.0287x over previous
//
#include <hip/hip_runtime.h>
#include <math.h>

// B=4, T=48, W=8, H=8, C=32; d_ff=64; periods {2,3,4}. T%P==0 always.
// (1x1 + 3^4)/2 inception folded into one 81-tap conv (center tap 40).
// Padded in L,P,W,H -> branch-free 81-tap loop.
// R5: R3 structure + explicit load batching (3-tap subgroups, high VGPR
// budget) + XCD-aware swizzle shared by conv1/conv2 for L2 slab locality.

typedef __attribute__((ext_vector_type(8))) short bf16x8;
typedef __attribute__((ext_vector_type(4))) float f32x4;
typedef unsigned short u16;

#define XB0 0
#define XB1 1331200            // 4 * 26*4*3200
#define XB2 2483200            // XB1 + 4 * 18*5*3200
#define XTOT 3558400           // XB2 + 4 * 14*6*3200
#define W1OFF XTOT             // 165888 bf16  [tap][o=64][c=32]
#define W2OFF (XTOT + 165888)  // 165888 bf16  [tap][o=32][c=64]
#define H1OFF (XTOT + 331776)  // h1pad3 (C=64)
#define HB0 0
#define HB1 2662400            // 4 * 26*4*6400
#define HB2 4966400            // HB1 + 4 * 18*5*6400
#define H1TOT 7116800
#define H2OFF_U16 (H1OFF + H1TOT)
#define H2_PER 393216          // fp32 per period: 192*64*32
#define PREP_N (XTOT + 331776)

__device__ __forceinline__ u16 f2bf(float f) {
    unsigned u = __float_as_uint(f);
    unsigned r = u + 0x7fffu + ((u >> 16) & 1u);
    return (u16)(r >> 16);
}
__device__ __forceinline__ float gelu_exact(float v) {
    return 0.5f * v * (1.0f + erff(v * 0.7071067811865476f));
}

// ---- prep: padded bf16 x (3 period layouts) + effective bf16 weights ----
__global__ __launch_bounds__(256) void prep(
    const float* __restrict__ x,
    const float* __restrict__ w1_0, const float* __restrict__ w1_1,
    const float* __restrict__ w2_0, const float* __restrict__ w2_1,
    u16* __restrict__ ws) {
    int i = blockIdx.x * 256 + threadIdx.x;
    if (i < XTOT) {
        int j, P, L;
        if (i < XB1)      { j = i;       P = 2; L = 24; }
        else if (i < XB2) { j = i - XB1; P = 3; L = 16; }
        else              { j = i - XB2; P = 4; L = 12; }
        int SZ = (L + 2) * (P + 2) * 3200;
        int b = j / SZ; int r = j - b * SZ;
        int c = r & 31; int s = r >> 5;
        int hp = s % 10; s /= 10;
        int wp = s % 10; s /= 10;
        int qp = s % (P + 2); int lp = s / (P + 2);
        float v = 0.f;
        if (lp >= 1 && lp <= L && qp >= 1 && qp <= P &&
            wp >= 1 && wp <= 8 && hp >= 1 && hp <= 8) {
            int t = (lp - 1) * P + (qp - 1);
            v = x[((b * 48 + t) * 64 + (wp - 1) * 8 + (hp - 1)) * 32 + c];
        }
        ws[i] = f2bf(v);
    } else if (i < W2OFF) {
        int j = i - W1OFF;
        int c = j & 31; int k = j >> 5;
        int o = k & 63; int tap = k >> 6;
        float v = 0.5f * w1_1[(o * 32 + c) * 81 + tap];
        if (tap == 40) v += 0.5f * w1_0[o * 32 + c];
        ws[i] = f2bf(v);
    } else if (i < PREP_N) {
        int j = i - W2OFF;
        int c = j & 63; int k = j >> 6;
        int o = k & 31; int tap = k >> 5;
        float v = 0.5f * w2_1[(o * 64 + c) * 81 + tap];
        if (tap == 40) v += 0.5f * w2_0[o * 64 + c];
        ws[i] = f2bf(v);
    }
}

// ---- conv1 (C32->C64) + GELU. Wave = one t, 32 out-ch half. ----
template<int P>
__device__ __forceinline__ void conv1_body(
    const u16* __restrict__ xpad, const u16* __restrict__ w1b,
    u16* __restrict__ h1pad, int half, int bt) {
    constexpr int L = 48 / P;
    constexpr int XB = (P == 2) ? XB0 : (P == 3) ? XB1 : XB2;
    constexpr int HB = (P == 2) ? HB0 : (P == 3) ? HB1 : HB2;
    constexpr int XSTR = (L + 2) * (P + 2) * 3200;
    constexpr int HSTR = (L + 2) * (P + 2) * 6400;

    int lane = threadIdx.x;
    int m = lane & 15, quad = lane >> 4;
    int b = bt / 48, t = bt - b * 48;
    int l = t / P, q = t - l * P;

    const u16* xb = xpad + XB + b * XSTR + (l * (P + 2) + q) * 3200;
    const u16* wb = w1b + (half * 32 + m) * 32 + quad * 8;

    int sp[4];
#pragma unroll
    for (int mt = 0; mt < 4; ++mt) {
        int pos = mt * 16 + m;
        sp[mt] = ((pos >> 3) * 10 + (pos & 7)) * 32 + quad * 8;
    }

    f32x4 acc[4][2];
#pragma unroll
    for (int mt = 0; mt < 4; ++mt)
#pragma unroll
        for (int nt = 0; nt < 2; ++nt) acc[mt][nt] = f32x4{0.f, 0.f, 0.f, 0.f};

#pragma unroll 1
    for (int dl = 0; dl < 3; ++dl) {
#pragma unroll
        for (int dq = 0; dq < 3; ++dq) {
            const u16* xt = xb + (dl * (P + 2) + dq) * 3200;
            const u16* wg = wb + (dl * 3 + dq) * 9 * 2048;
            // 3 subgroups of 3 taps; each batches 6 weight + 12 act loads
            // into registers before its 24 MFMAs (MLP ~18).
#pragma unroll
            for (int g = 0; g < 3; ++g) {
                bf16x8 wf[3][2];
                bf16x8 af[3][4];
#pragma unroll
                for (int j = 0; j < 3; ++j) {
                    int dwh = g * 3 + j;
                    int sd = ((dwh / 3) * 10 + (dwh % 3)) * 32;
                    wf[j][0] = *(const bf16x8*)(wg + dwh * 2048);
                    wf[j][1] = *(const bf16x8*)(wg + dwh * 2048 + 512);
#pragma unroll
                    for (int mt = 0; mt < 4; ++mt)
                        af[j][mt] = *(const bf16x8*)(xt + sp[mt] + sd);
                }
#pragma unroll
                for (int j = 0; j < 3; ++j)
#pragma unroll
                    for (int mt = 0; mt < 4; ++mt) {
                        acc[mt][0] = __builtin_amdgcn_mfma_f32_16x16x32_bf16(
                            af[j][mt], wf[j][0], acc[mt][0], 0, 0, 0);
                        acc[mt][1] = __builtin_amdgcn_mfma_f32_16x16x32_bf16(
                            af[j][mt], wf[j][1], acc[mt][1], 0, 0, 0);
                    }
            }
        }
    }

    u16* hb = h1pad + HB + b * HSTR + ((l + 1) * (P + 2) + (q + 1)) * 6400;
#pragma unroll
    for (int mt = 0; mt < 4; ++mt)
#pragma unroll
        for (int r = 0; r < 4; ++r) {
            int pos = mt * 16 + quad * 4 + r;
            int w = pos >> 3, h = pos & 7;
            u16* dst = hb + ((w + 1) * 10 + (h + 1)) * 64 + half * 32 + m;
#pragma unroll
            for (int nt = 0; nt < 2; ++nt)
                dst[nt * 16] = f2bf(gelu_exact(acc[mt][nt][r]));
        }
}

__global__ __launch_bounds__(64, 2) void conv1_k(
    const u16* __restrict__ ws_x, const u16* __restrict__ ws_w1,
    u16* __restrict__ ws_h1) {
    // XCD swizzle: blockIdx%8 = XCD (round-robin dispatch); give each XCD a
    // contiguous jid chunk so slab reuse hits its own L2. 1152 = 8*144.
    int g = blockIdx.x;
    int jid = (g & 7) * 144 + (g >> 3);
    int per = jid / 384; int rem = jid - per * 384;
    int half = rem / 192; int bt = rem - half * 192;
    if (per == 0)      conv1_body<2>(ws_x, ws_w1, ws_h1, half, bt);
    else if (per == 1) conv1_body<3>(ws_x, ws_w1, ws_h1, half, bt);
    else               conv1_body<4>(ws_x, ws_w1, ws_h1, half, bt);
}

// ---- conv2 (C64->C32). Wave = 32 positions (mh half) x 32 ch, K=64. ----
template<int P>
__device__ __forceinline__ void conv2_body(
    const u16* __restrict__ h1pad, const u16* __restrict__ w2b,
    float* __restrict__ orow, int mh, int bt) {
    constexpr int L = 48 / P;
    constexpr int HB = (P == 2) ? HB0 : (P == 3) ? HB1 : HB2;
    constexpr int HSTR = (L + 2) * (P + 2) * 6400;

    int lane = threadIdx.x;
    int m = lane & 15, quad = lane >> 4;
    int b = bt / 48, t = bt - b * 48;
    int l = t / P, q = t - l * P;

    const u16* hbb = h1pad + HB + b * HSTR + (l * (P + 2) + q) * 6400;
    const u16* wb = w2b + m * 64 + quad * 8;

    int sp[2];
#pragma unroll
    for (int mt = 0; mt < 2; ++mt) {
        int pos = mh * 32 + mt * 16 + m;
        sp[mt] = ((pos >> 3) * 10 + (pos & 7)) * 64 + quad * 8;
    }

    f32x4 acc[2][2];
#pragma unroll
    for (int mt = 0; mt < 2; ++mt)
#pragma unroll
        for (int nt = 0; nt < 2; ++nt) acc[mt][nt] = f32x4{0.f, 0.f, 0.f, 0.f};

#pragma unroll 1
    for (int dl = 0; dl < 3; ++dl) {
#pragma unroll
        for (int dq = 0; dq < 3; ++dq) {
            const u16* ht = hbb + (dl * (P + 2) + dq) * 6400;
            const u16* wg = wb + (dl * 3 + dq) * 9 * 2048;
            // 3 subgroups of 3 taps; batch 12 weight + 12 act loads.
#pragma unroll
            for (int g = 0; g < 3; ++g) {
                bf16x8 wf[3][2][2];   // [j][nt][ks]
                bf16x8 af[3][2][2];   // [j][mt][ks]
#pragma unroll
                for (int j = 0; j < 3; ++j) {
                    int dwh = g * 3 + j;
                    int sd = ((dwh / 3) * 10 + (dwh % 3)) * 64;
#pragma unroll
                    for (int nt = 0; nt < 2; ++nt)
#pragma unroll
                        for (int ks = 0; ks < 2; ++ks)
                            wf[j][nt][ks] = *(const bf16x8*)(
                                wg + dwh * 2048 + nt * 1024 + ks * 32);
#pragma unroll
                    for (int mt = 0; mt < 2; ++mt)
#pragma unroll
                        for (int ks = 0; ks < 2; ++ks)
                            af[j][mt][ks] = *(const bf16x8*)(
                                ht + sp[mt] + sd + ks * 32);
                }
#pragma unroll
                for (int j = 0; j < 3; ++j)
#pragma unroll
                    for (int mt = 0; mt < 2; ++mt)
#pragma unroll
                        for (int ks = 0; ks < 2; ++ks)
#pragma unroll
                            for (int nt = 0; nt < 2; ++nt)
                                acc[mt][nt] =
                                    __builtin_amdgcn_mfma_f32_16x16x32_bf16(
                                        af[j][mt][ks], wf[j][nt][ks],
                                        acc[mt][nt], 0, 0, 0);
            }
        }
    }

#pragma unroll
    for (int mt = 0; mt < 2; ++mt)
#pragma unroll
        for (int nt = 0; nt < 2; ++nt)
#pragma unroll
            for (int r = 0; r < 4; ++r) {
                int pos = mh * 32 + mt * 16 + quad * 4 + r;
                orow[pos * 32 + nt * 16 + m] = acc[mt][nt][r];
            }
}

__global__ __launch_bounds__(64, 2) void conv2_k(
    const u16* __restrict__ ws_h1, const u16* __restrict__ ws_w2,
    float* __restrict__ h2) {
    int g = blockIdx.x;
    int jid = (g & 7) * 144 + (g >> 3);   // same XCD mapping as conv1
    int per = jid / 384; int rem = jid - per * 384;
    int mh = rem / 192; int bt = rem - mh * 192;
    float* orow = h2 + per * H2_PER + bt * 2048;
    if (per == 0)      conv2_body<2>(ws_h1, ws_w2, orow, mh, bt);
    else if (per == 1) conv2_body<3>(ws_h1, ws_w2, orow, mh, bt);
    else               conv2_body<4>(ws_h1, ws_w2, orow, mh, bt);
}

// ---- out = x + (h2_p0 + h2_p1 + h2_p2) / 3 ----
__global__ __launch_bounds__(256) void final_add(
    const float* __restrict__ x, const float* __restrict__ h2,
    float* __restrict__ out) {
    int i = blockIdx.x * 256 + threadIdx.x;
    float4 xv = ((const float4*)x)[i];
    float4 a = ((const float4*)h2)[i];
    float4 bv = ((const float4*)(h2 + H2_PER))[i];
    float4 cv = ((const float4*)(h2 + 2 * H2_PER))[i];
    const float s = 1.0f / 3.0f;
    float4 o;
    o.x = xv.x + (a.x + bv.x + cv.x) * s;
    o.y = xv.y + (a.y + bv.y + cv.y) * s;
    o.z = xv.z + (a.z + bv.z + cv.z) * s;
    o.w = xv.w + (a.w + bv.w + cv.w) * s;
    ((float4*)out)[i] = o;
}

extern "C" void kernel_launch(void* const* d_in, const int* in_sizes, int n_in,
                              void* d_out, int out_size, void* d_ws, size_t ws_size,
                              hipStream_t stream) {
    const float* x    = (const float*)d_in[0];
    const float* w1_0 = (const float*)d_in[1];
    const float* w1_1 = (const float*)d_in[2];
    const float* w2_0 = (const float*)d_in[3];
    const float* w2_1 = (const float*)d_in[4];
    float* out = (float*)d_out;

    u16* ws = (u16*)d_ws;
    u16* ws_x  = ws;
    u16* ws_w1 = ws + W1OFF;
    u16* ws_w2 = ws + W2OFF;
    u16* ws_h1 = ws + H1OFF;
    float* h2  = (float*)(ws + H2OFF_U16);

    hipMemsetAsync(ws_h1, 0, (size_t)H1TOT * 2, stream);
    prep<<<PREP_N / 256, 256, 0, stream>>>(x, w1_0, w1_1, w2_0, w2_1, ws);
    conv1_k<<<1152, 64, 0, stream>>>(ws_x, ws_w1, ws_h1);
    conv2_k<<<1152, 64, 0, stream>>>(ws_h1, ws_w2, h2);
    final_add<<<H2_PER / 4 / 256, 256, 0, stream>>>(x, h2, out);
}

// Round 7
// 152.504 us; speedup vs baseline: 1.6302x; 1.5847x over previous
//
#include <hip/hip_runtime.h>
#include <math.h>

// B=4, T=48, W=8, H=8, C=32; d_ff=64; periods {2,3,4}. T%P==0 always.
// (1x1 + 3^4)/2 inception folded into one 81-tap conv (center tap 40).
// Padded in L,P,W,H -> branch-free 81 taps.
// R7 = R6 fixed: __shared__ hoisted out of template bodies (one LDS block
// per kernel, not per instantiation). Async global_load_lds staging,
// compute from LDS, XOR-swizzled layouts for low bank conflict.

typedef __attribute__((ext_vector_type(8))) short bf16x8;
typedef __attribute__((ext_vector_type(4))) float f32x4;
typedef unsigned short u16;

#define XB0 0
#define XB1 1331200            // 4 * 26*4*3200
#define XB2 2483200            // XB1 + 4 * 18*5*3200
#define XTOT 3558400           // XB2 + 4 * 14*6*3200
#define W1OFF XTOT             // 165888 bf16  [tap][chunk-swizzled o/c]
#define W2OFF (XTOT + 165888)  // 165888 bf16
#define H1OFF (XTOT + 331776)  // h1pad3 (C=64, swizzled cells)
#define HB0 0
#define HB1 2662400            // 4 * 26*4*6400
#define HB2 4966400            // HB1 + 4 * 18*5*6400
#define H1TOT 7116800
#define H2OFF_U16 (H1OFF + H1TOT)
#define H2_PER 393216          // fp32 per period: 192*64*32
#define PREP_N (XTOT + 331776)

__device__ __forceinline__ u16 f2bf(float f) {
    unsigned u = __float_as_uint(f);
    unsigned r = u + 0x7fffu + ((u >> 16) & 1u);
    return (u16)(r >> 16);
}
__device__ __forceinline__ float gelu_exact(float v) {
    return 0.5f * v * (1.0f + erff(v * 0.7071067811865476f));
}

// async copy of 1 KB: 64 lanes x 16 B. LDS dest = wave-uniform base + lane*16.
__device__ __forceinline__ void cp1k(const u16* g, u16* l, int lane) {
    __builtin_amdgcn_global_load_lds(
        (const __attribute__((address_space(1))) unsigned int*)(g + lane * 8),
        (__attribute__((address_space(3))) unsigned int*)(l + lane * 8),
        16, 0, 0);
}

// ---- prep: swizzled padded bf16 x + swizzled effective bf16 weights ----
// xpad cell (10x10x32): addr = cellpos*32 + sc*8 + (c&7), sc=(c>>3)^(cellpos&3)
// w1b per tap: chunk = (quad*4+nt)*16+m  -> element (o=nt*16+m, c=quad*8+j)
// w2b per tap: chunk = ((ks*4+quad)*2+nt)*16+m -> (o=nt*16+m, c=ks*32+quad*8+j)
__global__ __launch_bounds__(256) void prep(
    const float* __restrict__ x,
    const float* __restrict__ w1_0, const float* __restrict__ w1_1,
    const float* __restrict__ w2_0, const float* __restrict__ w2_1,
    u16* __restrict__ ws) {
    int i = blockIdx.x * 256 + threadIdx.x;
    if (i < XTOT) {
        int j, P, L;
        if (i < XB1)      { j = i;       P = 2; L = 24; }
        else if (i < XB2) { j = i - XB1; P = 3; L = 16; }
        else              { j = i - XB2; P = 4; L = 12; }
        int SZ = (L + 2) * (P + 2) * 3200;
        int b = j / SZ; int r = j - b * SZ;
        int cell2d = r / 3200; int inner = r - cell2d * 3200;
        int cellpos = inner >> 5; int low = inner & 31;
        int sc = low >> 3, jj = low & 7;
        int c = ((sc ^ (cellpos & 3)) << 3) + jj;
        int wp = cellpos / 10, hp = cellpos - (cellpos / 10) * 10;
        int qp = cell2d % (P + 2), lp = cell2d / (P + 2);
        float v = 0.f;
        if (lp >= 1 && lp <= L && qp >= 1 && qp <= P &&
            wp >= 1 && wp <= 8 && hp >= 1 && hp <= 8) {
            int t = (lp - 1) * P + (qp - 1);
            v = x[((b * 48 + t) * 64 + (wp - 1) * 8 + (hp - 1)) * 32 + c];
        }
        ws[i] = f2bf(v);
    } else if (i < W2OFF) {
        int j = i - W1OFF;
        int tap = j >> 11; int r = j & 2047;
        int chunk = r >> 3, jj = r & 7;
        int m = chunk & 15, nt = (chunk >> 4) & 3, quad = chunk >> 6;
        int o = nt * 16 + m, c = quad * 8 + jj;
        float v = 0.5f * w1_1[(o * 32 + c) * 81 + tap];
        if (tap == 40) v += 0.5f * w1_0[o * 32 + c];
        ws[i] = f2bf(v);
    } else if (i < PREP_N) {
        int j = i - W2OFF;
        int tap = j >> 11; int r = j & 2047;
        int chunk = r >> 3, jj = r & 7;
        int m = chunk & 15, nt = (chunk >> 4) & 1;
        int quad = (chunk >> 5) & 3, ks = chunk >> 7;
        int o = nt * 16 + m, c = ks * 32 + quad * 8 + jj;
        float v = 0.5f * w2_1[(o * 64 + c) * 81 + tap];
        if (tap == 40) v += 0.5f * w2_0[o * 64 + c];
        ws[i] = f2bf(v);
    }
}

// ---- conv1 (C32->C64) + GELU. Block = 2 waves; wave = one t, all 64 o. ----
template<int P>
__device__ __forceinline__ void conv1_body(
    const u16* __restrict__ xpad, const u16* __restrict__ w1b,
    u16* __restrict__ h1pad, int b, int tp,
    u16* __restrict__ s_w, u16* __restrict__ s_a) {
    constexpr int L = 48 / P;
    constexpr int XB = (P == 2) ? XB0 : (P == 3) ? XB1 : XB2;
    constexpr int HB = (P == 2) ? HB0 : (P == 3) ? HB1 : HB2;
    constexpr int XSTR = (L + 2) * (P + 2) * 3200;
    constexpr int HSTR = (L + 2) * (P + 2) * 6400;

    int tid = threadIdx.x;
    int lane = tid & 63, wv = tid >> 6;
    int m = lane & 15, quad = lane >> 4;
    int t = tp * 2 + wv;
    int l = t / P, q = t - l * P;

    const u16* xcell0 = xpad + XB + b * XSTR + (l * (P + 2) + q) * 3200;
    u16* s_aw = s_a + wv * 3584;

    f32x4 acc[4][4];
#pragma unroll
    for (int mt = 0; mt < 4; ++mt)
#pragma unroll
        for (int nt = 0; nt < 4; ++nt) acc[mt][nt] = f32x4{0.f, 0.f, 0.f, 0.f};

#pragma unroll 1
    for (int grp = 0; grp < 9; ++grp) {
        int dl = grp / 3, dq = grp - (grp / 3) * 3;
        if (grp) __syncthreads();          // prev compute done before overwrite
        const u16* wsrc = w1b + grp * (9 * 2048);
#pragma unroll
        for (int i = 0; i < 18; ++i)
            cp1k(wsrc + (wv * 18 + i) * 512, s_w + (wv * 18 + i) * 512, lane);
        const u16* asrc = xcell0 + (dl * (P + 2) + dq) * 3200;
#pragma unroll
        for (int i = 0; i < 7; ++i)        // 7 KB >= 6.4 KB cell (overread ok)
            cp1k(asrc + i * 512, s_aw + i * 512, lane);
        __builtin_amdgcn_s_waitcnt(0);
        __syncthreads();

#pragma unroll
        for (int dwh = 0; dwh < 9; ++dwh) {
            int dw = dwh / 3, dh = dwh - (dwh / 3) * 3;
            bf16x8 wf[4];
#pragma unroll
            for (int nt = 0; nt < 4; ++nt)
                wf[nt] = *(const bf16x8*)(s_w + dwh * 2048 +
                                          (((quad * 4 + nt) * 16 + m) << 3));
            bf16x8 af[4];
#pragma unroll
            for (int mt = 0; mt < 4; ++mt) {
                int pos = mt * 16 + m;
                int cellpos = ((pos >> 3) + dw) * 10 + (pos & 7) + dh;
                af[mt] = *(const bf16x8*)(s_aw + cellpos * 32 +
                                          ((quad ^ (cellpos & 3)) << 3));
            }
#pragma unroll
            for (int mt = 0; mt < 4; ++mt)
#pragma unroll
                for (int nt = 0; nt < 4; ++nt)
                    acc[mt][nt] = __builtin_amdgcn_mfma_f32_16x16x32_bf16(
                        af[mt], wf[nt], acc[mt][nt], 0, 0, 0);
        }
    }

    // epilogue: GELU -> bf16 -> swizzled h1pad cell (interior)
    u16* hcell = h1pad + HB + b * HSTR + ((l + 1) * (P + 2) + (q + 1)) * 6400;
#pragma unroll
    for (int mt = 0; mt < 4; ++mt)
#pragma unroll
        for (int r = 0; r < 4; ++r) {
            int pos = mt * 16 + quad * 4 + r;
            int cellpos = ((pos >> 3) + 1) * 10 + (pos & 7) + 1;
#pragma unroll
            for (int nt = 0; nt < 4; ++nt) {
                int o = nt * 16 + m;
                hcell[cellpos * 64 + (((o >> 3) ^ (cellpos & 7)) << 3) + (o & 7)] =
                    f2bf(gelu_exact(acc[mt][nt][r]));
            }
        }
}

__global__ __launch_bounds__(128) void conv1_k(
    const u16* __restrict__ ws_x, const u16* __restrict__ ws_w1,
    u16* __restrict__ ws_h1) {
    __shared__ __align__(16) u16 s_w[9 * 2048];   // 36 KB: 9 taps
    __shared__ __align__(16) u16 s_a[2 * 3584];   // 14 KB: 2 act cells
    int g = blockIdx.x;
    int jid = (g & 7) * 36 + (g >> 3);     // XCD-chunked
    int per = jid / 96; int rem = jid - per * 96;
    int b = rem / 24; int tp = rem - b * 24;
    if (per == 0)      conv1_body<2>(ws_x, ws_w1, ws_h1, b, tp, s_w, s_a);
    else if (per == 1) conv1_body<3>(ws_x, ws_w1, ws_h1, b, tp, s_w, s_a);
    else               conv1_body<4>(ws_x, ws_w1, ws_h1, b, tp, s_w, s_a);
}

// ---- conv2 (C64->C32). Block = 2 waves; wave = one t, all 32 o, K=64. ----
template<int P>
__device__ __forceinline__ void conv2_body(
    const u16* __restrict__ h1pad, const u16* __restrict__ w2b,
    float* __restrict__ h2per, int b, int tp,
    u16* __restrict__ s_w, u16* __restrict__ s_a) {
    constexpr int L = 48 / P;
    constexpr int HB = (P == 2) ? HB0 : (P == 3) ? HB1 : HB2;
    constexpr int HSTR = (L + 2) * (P + 2) * 6400;

    int tid = threadIdx.x;
    int lane = tid & 63, wv = tid >> 6;
    int m = lane & 15, quad = lane >> 4;
    int t = tp * 2 + wv;
    int l = t / P, q = t - l * P;

    const u16* hcell0 = h1pad + HB + b * HSTR + (l * (P + 2) + q) * 6400;
    u16* s_aw = s_a + wv * 6656;

    f32x4 acc[4][2];
#pragma unroll
    for (int mt = 0; mt < 4; ++mt)
#pragma unroll
        for (int nt = 0; nt < 2; ++nt) acc[mt][nt] = f32x4{0.f, 0.f, 0.f, 0.f};

#pragma unroll 1
    for (int grp = 0; grp < 9; ++grp) {
        int dl = grp / 3, dq = grp - (grp / 3) * 3;
        if (grp) __syncthreads();
        const u16* wsrc = w2b + grp * (9 * 2048);
#pragma unroll
        for (int i = 0; i < 18; ++i)
            cp1k(wsrc + (wv * 18 + i) * 512, s_w + (wv * 18 + i) * 512, lane);
        const u16* asrc = hcell0 + (dl * (P + 2) + dq) * 6400;
#pragma unroll
        for (int i = 0; i < 13; ++i)       // 13 KB >= 12.8 KB cell
            cp1k(asrc + i * 512, s_aw + i * 512, lane);
        __builtin_amdgcn_s_waitcnt(0);
        __syncthreads();

#pragma unroll
        for (int dwh = 0; dwh < 9; ++dwh) {
            int dw = dwh / 3, dh = dwh - (dwh / 3) * 3;
            bf16x8 wf[2][2];   // [nt][ks]
#pragma unroll
            for (int nt = 0; nt < 2; ++nt)
#pragma unroll
                for (int ks = 0; ks < 2; ++ks)
                    wf[nt][ks] = *(const bf16x8*)(s_w + dwh * 2048 +
                        ((((ks * 4 + quad) * 2 + nt) * 16 + m) << 3));
            bf16x8 af[4][2];   // [mt][ks]
#pragma unroll
            for (int mt = 0; mt < 4; ++mt) {
                int pos = mt * 16 + m;
                int cellpos = ((pos >> 3) + dw) * 10 + (pos & 7) + dh;
#pragma unroll
                for (int ks = 0; ks < 2; ++ks)
                    af[mt][ks] = *(const bf16x8*)(s_aw + cellpos * 64 +
                        (((ks * 4 + quad) ^ (cellpos & 7)) << 3));
            }
#pragma unroll
            for (int mt = 0; mt < 4; ++mt)
#pragma unroll
                for (int ks = 0; ks < 2; ++ks)
#pragma unroll
                    for (int nt = 0; nt < 2; ++nt)
                        acc[mt][nt] = __builtin_amdgcn_mfma_f32_16x16x32_bf16(
                            af[mt][ks], wf[nt][ks], acc[mt][nt], 0, 0, 0);
        }
    }

    float* orow = h2per + (b * 48 + t) * 2048;
#pragma unroll
    for (int mt = 0; mt < 4; ++mt)
#pragma unroll
        for (int nt = 0; nt < 2; ++nt)
#pragma unroll
            for (int r = 0; r < 4; ++r) {
                int pos = mt * 16 + quad * 4 + r;
                orow[pos * 32 + nt * 16 + m] = acc[mt][nt][r];
            }
}

__global__ __launch_bounds__(128) void conv2_k(
    const u16* __restrict__ ws_h1, const u16* __restrict__ ws_w2,
    float* __restrict__ h2) {
    __shared__ __align__(16) u16 s_w[9 * 2048];   // 36 KB
    __shared__ __align__(16) u16 s_a[2 * 6656];   // 26 KB
    int g = blockIdx.x;
    int jid = (g & 7) * 36 + (g >> 3);     // same XCD mapping as conv1
    int per = jid / 96; int rem = jid - per * 96;
    int b = rem / 24; int tp = rem - b * 24;
    float* h2per = h2 + per * H2_PER;
    if (per == 0)      conv2_body<2>(ws_h1, ws_w2, h2per, b, tp, s_w, s_a);
    else if (per == 1) conv2_body<3>(ws_h1, ws_w2, h2per, b, tp, s_w, s_a);
    else               conv2_body<4>(ws_h1, ws_w2, h2per, b, tp, s_w, s_a);
}

// ---- out = x + (h2_p0 + h2_p1 + h2_p2) / 3 ----
__global__ __launch_bounds__(256) void final_add(
    const float* __restrict__ x, const float* __restrict__ h2,
    float* __restrict__ out) {
    int i = blockIdx.x * 256 + threadIdx.x;
    float4 xv = ((const float4*)x)[i];
    float4 a = ((const float4*)h2)[i];
    float4 bv = ((const float4*)(h2 + H2_PER))[i];
    float4 cv = ((const float4*)(h2 + 2 * H2_PER))[i];
    const float s = 1.0f / 3.0f;
    float4 o;
    o.x = xv.x + (a.x + bv.x + cv.x) * s;
    o.y = xv.y + (a.y + bv.y + cv.y) * s;
    o.z = xv.z + (a.z + bv.z + cv.z) * s;
    o.w = xv.w + (a.w + bv.w + cv.w) * s;
    ((float4*)out)[i] = o;
}

extern "C" void kernel_launch(void* const* d_in, const int* in_sizes, int n_in,
                              void* d_out, int out_size, void* d_ws, size_t ws_size,
                              hipStream_t stream) {
    const float* x    = (const float*)d_in[0];
    const float* w1_0 = (const float*)d_in[1];
    const float* w1_1 = (const float*)d_in[2];
    const float* w2_0 = (const float*)d_in[3];
    const float* w2_1 = (const float*)d_in[4];
    float* out = (float*)d_out;

    u16* ws = (u16*)d_ws;
    u16* ws_x  = ws;
    u16* ws_w1 = ws + W1OFF;
    u16* ws_w2 = ws + W2OFF;
    u16* ws_h1 = ws + H1OFF;
    float* h2  = (float*)(ws + H2OFF_U16);

    (void)hipMemsetAsync(ws_h1, 0, (size_t)H1TOT * 2, stream);
    prep<<<PREP_N / 256, 256, 0, stream>>>(x, w1_0, w1_1, w2_0, w2_1, ws);
    conv1_k<<<288, 128, 0, stream>>>(ws_x, ws_w1, ws_h1);
    conv2_k<<<288, 128, 0, stream>>>(ws_h1, ws_w2, h2);
    final_add<<<H2_PER / 4 / 256, 256, 0, stream>>>(x, h2, out);
}